// Round 16
// baseline (45.883 us; speedup 1.0000x reference)
//
#include <hip/hip_runtime.h>

#define NT      2000
#define BATCH   4096
#define NODES   64
#define TBL_N   8192
#define JMAX    3.6f
#define ENTB    (TBL_N / 4)              // 2048 table blocks (4 waves, 1 entry each)
#define NCB     (BATCH / 256)            // 16 nc blocks
#define MAXIT   24
#define CHUNKS  ((NT + 255) / 256)       // 8 chunks of 256 steps (4/lane)

// ---------------- DPP cross-lane helpers (VALU, no DS latency) ----------------
template<int CTRL, int RMASK>
__device__ __forceinline__ float updpp(float oldv, float x) {
    return __int_as_float(__builtin_amdgcn_update_dpp(
        __float_as_int(oldv), __float_as_int(x), CTRL, RMASK, 0xF, false));
}
__device__ __forceinline__ float rdl63(float v) {
    return __int_as_float(__builtin_amdgcn_readlane(__float_as_int(v), 63));
}
__device__ __forceinline__ float rdl(float v, int k) {
    return __int_as_float(__builtin_amdgcn_readlane(__float_as_int(v), k));
}

// inclusive clamped-prefix (S,C) scan. compose: S=Sl+Sr ; C=max(Cl+Sr, Cr).
__device__ __forceinline__ void scan_sc(float& S, float& C) {
    const float NI = -3.0e38f;
    float Su, Cu;
    Su = updpp<0x111, 0xF>(0.0f, S); Cu = updpp<0x111, 0xF>(NI, C);
    C = fmaxf(Cu + S, C); S = Su + S;
    Su = updpp<0x112, 0xF>(0.0f, S); Cu = updpp<0x112, 0xF>(NI, C);
    C = fmaxf(Cu + S, C); S = Su + S;
    Su = updpp<0x114, 0xF>(0.0f, S); Cu = updpp<0x114, 0xF>(NI, C);
    C = fmaxf(Cu + S, C); S = Su + S;
    Su = updpp<0x118, 0xF>(0.0f, S); Cu = updpp<0x118, 0xF>(NI, C);
    C = fmaxf(Cu + S, C); S = Su + S;
    Su = updpp<0x142, 0xA>(0.0f, S); Cu = updpp<0x142, 0xA>(NI, C);
    C = fmaxf(Cu + S, C); S = Su + S;
    Su = updpp<0x143, 0xC>(0.0f, S); Cu = updpp<0x143, 0xC>(NI, C);
    C = fmaxf(Cu + S, C); S = Su + S;
}

// plain inclusive add-scan
__device__ __forceinline__ float scan_add(float S) {
    float Su;
    Su = updpp<0x111, 0xF>(0.0f, S); S += Su;
    Su = updpp<0x112, 0xF>(0.0f, S); S += Su;
    Su = updpp<0x114, 0xF>(0.0f, S); S += Su;
    Su = updpp<0x118, 0xF>(0.0f, S); S += Su;
    Su = updpp<0x142, 0xA>(0.0f, S); S += Su;
    Su = updpp<0x143, 0xC>(0.0f, S); S += Su;
    return S;
}

// kernel 1: [0,ENTB) float2 rho table (1 wave/entry, dual MLP eval) · [+NCB) nc
__global__ __launch_bounds__(256) void prep(
    const float* __restrict__ W1, const float* __restrict__ b1,
    const float* __restrict__ W2, const float* __restrict__ b2,
    const float* __restrict__ W3, const float* __restrict__ b3,
    const float* __restrict__ K,
    float2* __restrict__ tbl, int* __restrict__ ncArr) {
    if (blockIdx.x < ENTB) {
        const int lane = threadIdx.x & 63;
        const int idx = blockIdx.x * 4 + (threadIdx.x >> 6);
        const float h = JMAX / (float)TBL_N;
        const float ja = h * (float)idx;
        const float jb = ja + h;

        float w1 = W1[lane], bb1 = b1[lane];
        float h1a = fmaxf(fmaf(ja, w1, bb1), 0.0f);
        float h1b = fmaxf(fmaf(jb, w1, bb1), 0.0f);

        float acca = b2[lane], accb = acca;
#pragma unroll
        for (int k = 0; k < NODES; ++k) {
            float w2 = W2[k * NODES + lane];          // coalesced, L1-hot
            acca = fmaf(rdl(h1a, k), w2, acca);       // SALU broadcast
            accb = fmaf(rdl(h1b, k), w2, accb);
        }
        float w3 = W3[lane];
        float pa = fmaxf(acca, 0.0f) * w3;
        float pb = fmaxf(accb, 0.0f) * w3;
        float rhoa = rdl63(scan_add(pa)) + b3[0];
        float rhob = rdl63(scan_add(pb)) + b3[0];
        if (lane == 0) tbl[idx] = make_float2(rhoa, rhob - rhoa);
    } else {
        int b = (blockIdx.x - ENTB) * 256 + threadIdx.x;
        float Qmin = 3.3068376f * powf(K[b], 1.3333334f);
        int nc = 1 << 20;
        float Q = 0.0f;
        for (int o = 1; o <= 360; ++o) {
            float BC = 0.1f * (float)o;
            float jc = (0.14f * BC) * 0.125f;   // res == 50 exactly pre-cross
            Q = fmaf(jc, 0.1f, Q);
            if (Q > Qmin) { nc = o; break; }
        }
        ncArr[b] = min(nc, NT - 1);
    }
}

// kernel 2: fused parallel-in-time solve + expansion; writes all 4 planes.
// ONE WAVE per chain; 4 steps/lane; 8 chunks of 256 steps.
__global__ __launch_bounds__(64, 4) void fused(
    const float* __restrict__ Cv, const float* __restrict__ jmin,
    const int* __restrict__ ncArr, const float2* __restrict__ tbl,
    float* __restrict__ out) {
    const float NI = -3.0e38f;
    const int lane = threadIdx.x;
    const int b = blockIdx.x;
    const float cv = Cv[b];
    const float jm = jmin[b];
    const int   nc = ncArr[b];
    const float k1    = cv * 0.1f;
    const float nk1jm = -k1 * jm;
    const float invh  = (float)TBL_N / JMAX;

    float* __restrict__ oT  = out + (size_t)b * NT;
    float* __restrict__ oR  = out + (size_t)BATCH * NT + (size_t)b * NT;
    float* __restrict__ oC  = out + 2 * (size_t)BATCH * NT + (size_t)b * NT;
    float* __restrict__ oTm = out + 3 * (size_t)BATCH * NT + (size_t)b * NT;

    float carry = 50.0f, slope = 0.0f, curv = 0.0f;
    float y = 0.0f;

    for (int c = 0; c < CHUNKS; ++c) {
        const int ob = c << 8;
        const int o0 = ob + 4 * lane, o1 = o0 + 1, o2 = o0 + 2, o3 = o0 + 3;
        const int q = (ob >> 2) + lane;

        const float tm0 = 0.1f * (float)o0, tm1 = 0.1f * (float)o1;
        const float tm2 = 0.1f * (float)o2, tm3 = 0.1f * (float)o3;
        const float co0 = 0.14f * tm0, co1 = 0.14f * tm1;
        const float co2 = 0.14f * tm2, co3 = 0.14f * tm3;
        const bool a0 = (o0 >= nc) && (o0 < NT);
        const bool a1 = (o1 >= nc) && (o1 < NT);
        const bool a2 = (o2 >= nc) && (o2 < NT);
        const bool a3 = (o3 >= nc) && (o3 < NT);

        // quadratic warm start
        const float s0 = (float)(4 * lane + 1);
        float g0 = fmaf(fmaf(curv, s0, slope), s0, carry);
        const float s1 = s0 + 1.0f;
        float g1 = fmaf(fmaf(curv, s1, slope), s1, carry);
        const float s2 = s0 + 2.0f;
        float g2 = fmaf(fmaf(curv, s2, slope), s2, carry);
        const float s3 = s0 + 3.0f;
        float g3 = fmaf(fmaf(curv, s3, slope), s3, carry);

        float j0, j1, j2, j3, n0, n1, n2, n3;
        for (int it = 0; it < MAXIT; ++it) {
            float rp0 = updpp<0x138, 0xF>(carry, g3);   // wave_shr1, lane0=carry
            j0 = co0 * __builtin_amdgcn_rcpf(fmaf(0.14f, rp0, 1.0f));
            j1 = co1 * __builtin_amdgcn_rcpf(fmaf(0.14f, g0, 1.0f));
            j2 = co2 * __builtin_amdgcn_rcpf(fmaf(0.14f, g1, 1.0f));
            j3 = co3 * __builtin_amdgcn_rcpf(fmaf(0.14f, g2, 1.0f));

            float x0 = fminf(fmaxf(j0 * invh, 0.0f), (float)(TBL_N - 2));
            float x1 = fminf(fmaxf(j1 * invh, 0.0f), (float)(TBL_N - 2));
            float x2 = fminf(fmaxf(j2 * invh, 0.0f), (float)(TBL_N - 2));
            float x3 = fminf(fmaxf(j3 * invh, 0.0f), (float)(TBL_N - 2));
            int ip0 = (int)x0, ip1 = (int)x1, ip2 = (int)x2, ip3 = (int)x3;
            float2 vd0 = tbl[ip0], vd1 = tbl[ip1], vd2 = tbl[ip2], vd3 = tbl[ip3];
            float rho0 = fmaf(x0 - (float)ip0, vd0.y, vd0.x);
            float rho1 = fmaf(x1 - (float)ip1, vd1.y, vd1.x);
            float rho2 = fmaf(x2 - (float)ip2, vd2.y, vd2.x);
            float rho3 = fmaf(x3 - (float)ip3, vd3.y, vd3.x);

            n0 = fmaf(k1, j0, nk1jm); n1 = fmaf(k1, j1, nk1jm);
            n2 = fmaf(k1, j2, nk1jm); n3 = fmaf(k1, j3, nk1jm);
            float i0 = a0 ? rho0 * n0 : 0.0f;
            float i1 = a1 ? rho1 * n1 : 0.0f;
            float i2 = a2 ? rho2 * n2 : 0.0f;
            float i3 = a3 ? rho3 * n3 : 0.0f;

            float LS0 = i0, LS1 = LS0 + i1, LS2 = LS1 + i2, LS3 = LS2 + i3;

            // fast path: plain add-scan; valid iff no prefix dips below 50
            float Sp = scan_add(LS3);
            float Se = updpp<0x138, 0xF>(0.0f, Sp);
            float r0 = carry + (Se + LS0);
            float r1 = carry + (Se + LS1);
            float r2 = carry + (Se + LS2);
            float r3 = carry + (Se + LS3);
            float mn = fminf(fminf(r0, r1), fminf(r2, r3));
            if (!__all(mn >= 50.0f)) {
                float c0 = a0 ? 50.0f : NI, c1 = a1 ? 50.0f : NI;
                float c2 = a2 ? 50.0f : NI, c3 = a3 ? 50.0f : NI;
                float LC0 = c0;
                float LC1 = fmaxf(LC0 + i1, c1);
                float LC2 = fmaxf(LC1 + i2, c2);
                float LC3 = fmaxf(LC2 + i3, c3);
                float Sw = LS3, Cw = LC3;
                scan_sc(Sw, Cw);
                float Sx = updpp<0x138, 0xF>(0.0f, Sw);
                float Cx = updpp<0x138, 0xF>(NI, Cw);
                r0 = fmaxf(carry + (Sx + LS0), fmaxf(Cx + LS0, LC0));
                r1 = fmaxf(carry + (Sx + LS1), fmaxf(Cx + LS1, LC1));
                r2 = fmaxf(carry + (Sx + LS2), fmaxf(Cx + LS2, LC2));
                r3 = fmaxf(carry + (Sx + LS3), fmaxf(Cx + LS3, LC3));
            }

            float d = fmaxf(fmaxf(fabsf(r0 - g0), fabsf(r1 - g1)),
                            fmaxf(fabsf(r2 - g2), fabsf(r3 - g3)));
            g0 = r0; g1 = r1; g2 = r2; g3 = r3;
            if (__all(d <= 1.0e-3f)) break;
        }

        // thk: plain prefix of tinc (all increments > 0 post-cross; never clamps)
        {
            float i0 = a0 ? n0 : 0.0f, i1 = a1 ? n1 : 0.0f;
            float i2 = a2 ? n2 : 0.0f, i3 = a3 ? n3 : 0.0f;
            float LS0 = i0, LS1 = LS0 + i1, LS2 = LS1 + i2, LS3 = LS2 + i3;
            float Sp = scan_add(LS3);
            float Se = updpp<0x138, 0xF>(0.0f, Sp);
            float t0 = y + (Se + LS0);
            float t1 = y + (Se + LS1);
            float t2 = y + (Se + LS2);
            float t3 = y + (Se + LS3);

            if (o0 == 0) j0 = 1e-3f;

            if (o3 < NT) {
                reinterpret_cast<float4*>(oT)[q]  = make_float4(t0, t1, t2, t3);
                reinterpret_cast<float4*>(oR)[q]  = make_float4(g0, g1, g2, g3);
                reinterpret_cast<float4*>(oC)[q]  = make_float4(j0, j1, j2, j3);
                reinterpret_cast<float4*>(oTm)[q] = make_float4(tm0, tm1, tm2, tm3);
            }
            y = rdl63(t3);
        }

        float lastR = rdl63(g3);
        float ns = (lastR - carry) * 0.00390625f;
        curv = (ns - slope) * 0.001953125f;
        slope = ns;
        carry = lastR;
    }
}

extern "C" void kernel_launch(void* const* d_in, const int* in_sizes, int n_in,
                              void* d_out, int out_size, void* d_ws, size_t ws_size,
                              hipStream_t stream) {
    const float* Cv   = (const float*)d_in[0];
    const float* K    = (const float*)d_in[1];
    const float* jmin = (const float*)d_in[2];
    const float* W1   = (const float*)d_in[3];
    const float* b1   = (const float*)d_in[4];
    const float* W2   = (const float*)d_in[5];
    const float* b2   = (const float*)d_in[6];
    const float* W3   = (const float*)d_in[7];
    const float* b3   = (const float*)d_in[8];
    float* out = (float*)d_out;
    float2* tbl = (float2*)d_ws;                                 // 64 KB
    int*    ncA = (int*)((char*)d_ws + TBL_N * sizeof(float2));  // 16 KB

    prep<<<ENTB + NCB, 256, 0, stream>>>(W1, b1, W2, b2, W3, b3, K, tbl, ncA);
    fused<<<BATCH, 64, 0, stream>>>(Cv, jmin, ncA, tbl, out);
}

// Round 18
// 40.359 us; speedup vs baseline: 1.1369x; 1.1369x over previous
//
#include <hip/hip_runtime.h>

#define NT      2000
#define BATCH   4096
#define NODES   64
#define TBL_N   2048                     // 16 KB float2 table -> L1-resident
#define JMAX    3.6f
#define ENTB    (TBL_N / 4)              // 512 table blocks (4 waves, 1 entry each)
#define NCB     (BATCH / 256)            // 16 nc blocks
#define FILLB   (BATCH * NT / 4 / 256)   // 8000 time-plane fill blocks
#define MAXIT   24
#define CHUNKS  ((NT + 255) / 256)       // 8 chunks of 256 steps (4/lane)

typedef float floatx4 __attribute__((ext_vector_type(4)));

// ---------------- DPP cross-lane helpers (VALU, no DS latency) ----------------
template<int CTRL, int RMASK>
__device__ __forceinline__ float updpp(float oldv, float x) {
    return __int_as_float(__builtin_amdgcn_update_dpp(
        __float_as_int(oldv), __float_as_int(x), CTRL, RMASK, 0xF, false));
}
__device__ __forceinline__ float rdl63(float v) {
    return __int_as_float(__builtin_amdgcn_readlane(__float_as_int(v), 63));
}
__device__ __forceinline__ float rdl(float v, int k) {
    return __int_as_float(__builtin_amdgcn_readlane(__float_as_int(v), k));
}
__device__ __forceinline__ void ntst4(float* p, float a, float b, float c, float d) {
    floatx4 v = { a, b, c, d };
    __builtin_nontemporal_store(v, reinterpret_cast<floatx4*>(p));
}

// inclusive clamped-prefix (S,C) scan. compose: S=Sl+Sr ; C=max(Cl+Sr, Cr).
__device__ __forceinline__ void scan_sc(float& S, float& C) {
    const float NI = -3.0e38f;
    float Su, Cu;
    Su = updpp<0x111, 0xF>(0.0f, S); Cu = updpp<0x111, 0xF>(NI, C);
    C = fmaxf(Cu + S, C); S = Su + S;
    Su = updpp<0x112, 0xF>(0.0f, S); Cu = updpp<0x112, 0xF>(NI, C);
    C = fmaxf(Cu + S, C); S = Su + S;
    Su = updpp<0x114, 0xF>(0.0f, S); Cu = updpp<0x114, 0xF>(NI, C);
    C = fmaxf(Cu + S, C); S = Su + S;
    Su = updpp<0x118, 0xF>(0.0f, S); Cu = updpp<0x118, 0xF>(NI, C);
    C = fmaxf(Cu + S, C); S = Su + S;
    Su = updpp<0x142, 0xA>(0.0f, S); Cu = updpp<0x142, 0xA>(NI, C);
    C = fmaxf(Cu + S, C); S = Su + S;
    Su = updpp<0x143, 0xC>(0.0f, S); Cu = updpp<0x143, 0xC>(NI, C);
    C = fmaxf(Cu + S, C); S = Su + S;
}

// plain inclusive add-scan
__device__ __forceinline__ float scan_add(float S) {
    float Su;
    Su = updpp<0x111, 0xF>(0.0f, S); S += Su;
    Su = updpp<0x112, 0xF>(0.0f, S); S += Su;
    Su = updpp<0x114, 0xF>(0.0f, S); S += Su;
    Su = updpp<0x118, 0xF>(0.0f, S); S += Su;
    Su = updpp<0x142, 0xA>(0.0f, S); S += Su;
    Su = updpp<0x143, 0xC>(0.0f, S); S += Su;
    return S;
}

// kernel 1: [0,ENTB) float2 rho table (1 wave/entry) · [+NCB) nc · [+FILLB) time
__global__ __launch_bounds__(256) void prep(
    const float* __restrict__ W1, const float* __restrict__ b1,
    const float* __restrict__ W2, const float* __restrict__ b2,
    const float* __restrict__ W3, const float* __restrict__ b3,
    const float* __restrict__ K,
    float2* __restrict__ tbl, int* __restrict__ ncArr,
    float* __restrict__ out) {
    if (blockIdx.x < ENTB) {
        const int lane = threadIdx.x & 63;
        const int idx = blockIdx.x * 4 + (threadIdx.x >> 6);
        const float h = JMAX / (float)TBL_N;
        const float ja = h * (float)idx;
        const float jb = ja + h;

        float w1 = W1[lane], bb1 = b1[lane];
        float h1a = fmaxf(fmaf(ja, w1, bb1), 0.0f);
        float h1b = fmaxf(fmaf(jb, w1, bb1), 0.0f);

        float acca = b2[lane], accb = acca;
#pragma unroll
        for (int k = 0; k < NODES; ++k) {
            float w2 = W2[k * NODES + lane];          // coalesced, L1-hot
            acca = fmaf(rdl(h1a, k), w2, acca);       // SALU broadcast
            accb = fmaf(rdl(h1b, k), w2, accb);
        }
        float w3 = W3[lane];
        float pa = fmaxf(acca, 0.0f) * w3;
        float pb = fmaxf(accb, 0.0f) * w3;
        float rhoa = rdl63(scan_add(pa)) + b3[0];
        float rhob = rdl63(scan_add(pb)) + b3[0];
        if (lane == 0) tbl[idx] = make_float2(rhoa, rhob - rhoa);
    } else if (blockIdx.x < ENTB + NCB) {
        int b = (blockIdx.x - ENTB) * 256 + threadIdx.x;
        float Qmin = 3.3068376f * powf(K[b], 1.3333334f);
        int nc = 1 << 20;
        float Q = 0.0f;
        for (int o = 1; o <= 360; ++o) {
            float BC = 0.1f * (float)o;
            float jc = (0.14f * BC) * 0.125f;   // res == 50 exactly pre-cross
            Q = fmaf(jc, 0.1f, Q);
            if (Q > Qmin) { nc = o; break; }
        }
        ncArr[b] = min(nc, NT - 1);
    } else {
        int e = (blockIdx.x - ENTB - NCB) * 256 + threadIdx.x;   // float4 idx
        int t0 = (e * 4) % NT;                                   // NT % 4 == 0
        ntst4(out + 3 * (size_t)BATCH * NT + 4 * (size_t)e,
              0.1f * (float)t0, 0.1f * (float)(t0 + 1),
              0.1f * (float)(t0 + 2), 0.1f * (float)(t0 + 3));
    }
}

// kernel 2: fused parallel-in-time solve + expansion (thk, res, current planes).
// ONE WAVE per chain; 4 steps/lane; 8 chunks of 256 steps; L1-resident table.
__global__ __launch_bounds__(64, 4) void fused(
    const float* __restrict__ Cv, const float* __restrict__ jmin,
    const int* __restrict__ ncArr, const float2* __restrict__ tbl,
    float* __restrict__ out) {
    const float NI = -3.0e38f;
    const int lane = threadIdx.x;
    const int b = blockIdx.x;
    const float cv = Cv[b];
    const float jm = jmin[b];
    const int   nc = ncArr[b];
    const float k1    = cv * 0.1f;
    const float nk1jm = -k1 * jm;
    const float invh  = (float)TBL_N / JMAX;

    float* __restrict__ oT  = out + (size_t)b * NT;
    float* __restrict__ oR  = out + (size_t)BATCH * NT + (size_t)b * NT;
    float* __restrict__ oC  = out + 2 * (size_t)BATCH * NT + (size_t)b * NT;

    float carry = 50.0f, slope = 0.0f, curv = 0.0f;
    float y = 0.0f;

    for (int c = 0; c < CHUNKS; ++c) {
        const int ob = c << 8;
        const int o0 = ob + 4 * lane, o1 = o0 + 1, o2 = o0 + 2, o3 = o0 + 3;
        const int q4 = ob + 4 * lane;              // float offset of this lane's 4

        const float tm0 = 0.1f * (float)o0, tm1 = 0.1f * (float)o1;
        const float tm2 = 0.1f * (float)o2, tm3 = 0.1f * (float)o3;
        const float co0 = 0.14f * tm0, co1 = 0.14f * tm1;
        const float co2 = 0.14f * tm2, co3 = 0.14f * tm3;
        const bool a0 = (o0 >= nc) && (o0 < NT);
        const bool a1 = (o1 >= nc) && (o1 < NT);
        const bool a2 = (o2 >= nc) && (o2 < NT);
        const bool a3 = (o3 >= nc) && (o3 < NT);

        // quadratic warm start
        const float s0 = (float)(4 * lane + 1);
        float g0 = fmaf(fmaf(curv, s0, slope), s0, carry);
        const float s1 = s0 + 1.0f;
        float g1 = fmaf(fmaf(curv, s1, slope), s1, carry);
        const float s2 = s0 + 2.0f;
        float g2 = fmaf(fmaf(curv, s2, slope), s2, carry);
        const float s3 = s0 + 3.0f;
        float g3 = fmaf(fmaf(curv, s3, slope), s3, carry);

        float j0, j1, j2, j3, n0, n1, n2, n3;
        for (int it = 0; it < MAXIT; ++it) {
            float rp0 = updpp<0x138, 0xF>(carry, g3);   // wave_shr1, lane0=carry
            j0 = co0 * __builtin_amdgcn_rcpf(fmaf(0.14f, rp0, 1.0f));
            j1 = co1 * __builtin_amdgcn_rcpf(fmaf(0.14f, g0, 1.0f));
            j2 = co2 * __builtin_amdgcn_rcpf(fmaf(0.14f, g1, 1.0f));
            j3 = co3 * __builtin_amdgcn_rcpf(fmaf(0.14f, g2, 1.0f));

            float x0 = fminf(fmaxf(j0 * invh, 0.0f), (float)(TBL_N - 2));
            float x1 = fminf(fmaxf(j1 * invh, 0.0f), (float)(TBL_N - 2));
            float x2 = fminf(fmaxf(j2 * invh, 0.0f), (float)(TBL_N - 2));
            float x3 = fminf(fmaxf(j3 * invh, 0.0f), (float)(TBL_N - 2));
            int ip0 = (int)x0, ip1 = (int)x1, ip2 = (int)x2, ip3 = (int)x3;
            float2 vd0 = tbl[ip0], vd1 = tbl[ip1], vd2 = tbl[ip2], vd3 = tbl[ip3];
            float rho0 = fmaf(x0 - (float)ip0, vd0.y, vd0.x);
            float rho1 = fmaf(x1 - (float)ip1, vd1.y, vd1.x);
            float rho2 = fmaf(x2 - (float)ip2, vd2.y, vd2.x);
            float rho3 = fmaf(x3 - (float)ip3, vd3.y, vd3.x);

            n0 = fmaf(k1, j0, nk1jm); n1 = fmaf(k1, j1, nk1jm);
            n2 = fmaf(k1, j2, nk1jm); n3 = fmaf(k1, j3, nk1jm);
            float i0 = a0 ? rho0 * n0 : 0.0f;
            float i1 = a1 ? rho1 * n1 : 0.0f;
            float i2 = a2 ? rho2 * n2 : 0.0f;
            float i3 = a3 ? rho3 * n3 : 0.0f;

            float LS0 = i0, LS1 = LS0 + i1, LS2 = LS1 + i2, LS3 = LS2 + i3;

            // fast path: plain add-scan; valid iff no prefix dips below 50
            float Sp = scan_add(LS3);
            float Se = updpp<0x138, 0xF>(0.0f, Sp);
            float r0 = carry + (Se + LS0);
            float r1 = carry + (Se + LS1);
            float r2 = carry + (Se + LS2);
            float r3 = carry + (Se + LS3);
            float mn = fminf(fminf(r0, r1), fminf(r2, r3));
            if (!__all(mn >= 50.0f)) {
                float c0 = a0 ? 50.0f : NI, c1 = a1 ? 50.0f : NI;
                float c2 = a2 ? 50.0f : NI, c3 = a3 ? 50.0f : NI;
                float LC0 = c0;
                float LC1 = fmaxf(LC0 + i1, c1);
                float LC2 = fmaxf(LC1 + i2, c2);
                float LC3 = fmaxf(LC2 + i3, c3);
                float Sw = LS3, Cw = LC3;
                scan_sc(Sw, Cw);
                float Sx = updpp<0x138, 0xF>(0.0f, Sw);
                float Cx = updpp<0x138, 0xF>(NI, Cw);
                r0 = fmaxf(carry + (Sx + LS0), fmaxf(Cx + LS0, LC0));
                r1 = fmaxf(carry + (Sx + LS1), fmaxf(Cx + LS1, LC1));
                r2 = fmaxf(carry + (Sx + LS2), fmaxf(Cx + LS2, LC2));
                r3 = fmaxf(carry + (Sx + LS3), fmaxf(Cx + LS3, LC3));
            }

            float d = fmaxf(fmaxf(fabsf(r0 - g0), fabsf(r1 - g1)),
                            fmaxf(fabsf(r2 - g2), fabsf(r3 - g3)));
            g0 = r0; g1 = r1; g2 = r2; g3 = r3;
            if (__all(d <= 1.0e-3f)) break;
        }

        // thk: plain prefix of tinc (never clamps post-crossing)
        {
            float i0 = a0 ? n0 : 0.0f, i1 = a1 ? n1 : 0.0f;
            float i2 = a2 ? n2 : 0.0f, i3 = a3 ? n3 : 0.0f;
            float LS0 = i0, LS1 = LS0 + i1, LS2 = LS1 + i2, LS3 = LS2 + i3;
            float Sp = scan_add(LS3);
            float Se = updpp<0x138, 0xF>(0.0f, Sp);
            float t0 = y + (Se + LS0);
            float t1 = y + (Se + LS1);
            float t2 = y + (Se + LS2);
            float t3 = y + (Se + LS3);

            if (o0 == 0) j0 = 1e-3f;

            if (o3 < NT) {
                ntst4(oT + q4, t0, t1, t2, t3);
                ntst4(oR + q4, g0, g1, g2, g3);
                ntst4(oC + q4, j0, j1, j2, j3);
            }
            y = rdl63(t3);
        }

        float lastR = rdl63(g3);
        float ns = (lastR - carry) * 0.00390625f;
        curv = (ns - slope) * 0.001953125f;
        slope = ns;
        carry = lastR;
    }
}

extern "C" void kernel_launch(void* const* d_in, const int* in_sizes, int n_in,
                              void* d_out, int out_size, void* d_ws, size_t ws_size,
                              hipStream_t stream) {
    const float* Cv   = (const float*)d_in[0];
    const float* K    = (const float*)d_in[1];
    const float* jmin = (const float*)d_in[2];
    const float* W1   = (const float*)d_in[3];
    const float* b1   = (const float*)d_in[4];
    const float* W2   = (const float*)d_in[5];
    const float* b2   = (const float*)d_in[6];
    const float* W3   = (const float*)d_in[7];
    const float* b3   = (const float*)d_in[8];
    float* out = (float*)d_out;
    float2* tbl = (float2*)d_ws;                                 // 16 KB
    int*    ncA = (int*)((char*)d_ws + TBL_N * sizeof(float2));  // 16 KB

    prep<<<ENTB + NCB + FILLB, 256, 0, stream>>>(
        W1, b1, W2, b2, W3, b3, K, tbl, ncA, out);
    fused<<<BATCH, 64, 0, stream>>>(Cv, jmin, ncA, tbl, out);
}